// Round 4
// baseline (797.870 us; speedup 1.0000x reference)
//
#include <hip/hip_runtime.h>
#include <hip/hip_bf16.h>

#define ALPHA_ 0.2f
#define EPS_ 1e-12f

typedef short short8 __attribute__((ext_vector_type(8)));
typedef float f32x4 __attribute__((ext_vector_type(4)));

constexpr int BB = 16, KK = 16, DD = 256, NNEG = 16384;
constexpr int ITERS = 5;   // Newton-Schulz iterations (odd => final lands in XB)

// ---- workspace layout (float offsets) ---- total 5,309,440 floats <= proven 21.2 MB
// Newton phase:            after Newton (XB holds final A; XA/T/S dead):
constexpr size_t OFF_C01   = 0;         // 32 floats: c0[16], c1[16] (dead after kinitx)
constexpr size_t OFF_NL    = 0;         // 2M floats: neg-lo (overlays C01+XA)
constexpr size_t OFF_XA_H  = 1048576;
constexpr size_t OFF_XA_L  = 1572864;
constexpr size_t OFF_XB_H  = 2097152;   // FINAL A hi
constexpr size_t OFF_XB_L  = 2621440;   // FINAL A lo
constexpr size_t OFF_NH    = 3145728;   // 2M floats: neg-hi (overlays T+S)
constexpr size_t OFF_T_H   = 3145728;
constexpr size_t OFF_T_L   = 3670016;
constexpr size_t OFF_S_H   = 4194304;
constexpr size_t OFF_S_L   = 4718592;
constexpr size_t OFF_PA_H  = 5242880;   // 65536 ushorts
constexpr size_t OFF_PA_L  = 5275648;
constexpr size_t OFF_PAP   = 5308416;
constexpr size_t OFF_DPOS2 = 5308672;
constexpr size_t OFF_MINA  = 5308928;
constexpr size_t OFF_MINV  = 5309184;

// ---------- bf16 split helpers (RNE) ----------
__device__ inline unsigned short bf_hi(float x) {
    unsigned u = __float_as_uint(x);
    return (unsigned short)((u + 0x7fffu + ((u >> 16) & 1u)) >> 16);
}
__device__ inline float bf_tof(unsigned short h) { return __uint_as_float(((unsigned)h) << 16); }
__device__ inline void split2(float x, unsigned short& h, unsigned short& l) {
    h = bf_hi(x); l = bf_hi(x - bf_tof(h));
}

// ---------- Gershgorin bound -> degree-2 minimax init coefficients ----------
// X0 = c0*I + c1*S with c1 = -2/(G + (G+1)^2/4), c0 = -c1*(G+1); rho0 = |1 + c1*G| ~ 0.62
__global__ __launch_bounds__(256) void kbound(const float* __restrict__ Sig, float* __restrict__ ws) {
    int b = blockIdx.x, t = threadIdx.x;
    const float* S = Sig + (size_t)b * 65536;
    __shared__ float red[256];
    float cs = 0.f;
    for (int i = 0; i < 256; ++i) cs += fabsf(S[(size_t)i * 256 + t]);
    red[t] = cs; __syncthreads();
    for (int s = 128; s > 0; s >>= 1) { if (t < s) red[t] = fmaxf(red[t], red[t + s]); __syncthreads(); }
    if (t == 0) {
        float G = red[0];                       // guaranteed >= lambda_max; lambda_min >= 1 (Sigma = I + RR'/D)
        float c1 = -2.f / (G + (G + 1.f) * (G + 1.f) * 0.25f);
        float c0 = -c1 * (G + 1.f);
        ws[OFF_C01 + b] = c0; ws[OFF_C01 + 16 + b] = c1;
    }
}

// ---------- fp32 -> bf16 hi/lo split for Sigma ----------
__global__ __launch_bounds__(256) void ksplitS(const float* __restrict__ in,
                                               unsigned short* __restrict__ h,
                                               unsigned short* __restrict__ l, int n) {
    int i = blockIdx.x * 256 + threadIdx.x;
    if (i < n) { unsigned short hh, ll; split2(in[i], hh, ll); h[i] = hh; l[i] = ll; }
}

// ---------- X0 = c0*I + c1*S (split) ----------
__global__ __launch_bounds__(256) void kinitx(const float* __restrict__ Sig, float* __restrict__ ws) {
    int idx = blockIdx.x * 256 + threadIdx.x;     // < 16*65536
    int b = idx >> 16, rc = idx & 65535;
    int r = rc >> 8, c = rc & 255;
    float c0 = ws[OFF_C01 + b], c1 = ws[OFF_C01 + 16 + b];
    float v = c1 * Sig[idx] + ((r == c) ? c0 : 0.f);
    unsigned short h, l; split2(v, h, l);
    ((unsigned short*)(ws + OFF_XA_H))[idx] = h;
    ((unsigned short*)(ws + OFF_XA_L))[idx] = l;
}

// ---------- batched 256x256 MFMA split GEMM, 32x64 tiles, 512 blocks (2/CU) ----------
// operands symmetric & commuting: B-frags read rows. mode2i: C = 2I - A@B.
__global__ __launch_bounds__(256) void gemm_mfma(const unsigned short* __restrict__ Ah,
                                                 const unsigned short* __restrict__ Al,
                                                 const unsigned short* __restrict__ Bh,
                                                 const unsigned short* __restrict__ Bl,
                                                 unsigned short* __restrict__ Ch,
                                                 unsigned short* __restrict__ Cl, int mode2i) {
    int b = blockIdx.y;
    int i0 = (blockIdx.x >> 2) * 32, j0 = (blockIdx.x & 3) * 64;
    size_t base = (size_t)b * 65536;
    int t = threadIdx.x, lane = t & 63, w = t >> 6;
    int l15 = lane & 15, lg = lane >> 4;
    f32x4 acc[2] = {};
    int ar0 = i0 + l15;
    int br  = j0 + w * 16 + l15;
    #pragma unroll
    for (int e0 = 0; e0 < 256; e0 += 32) {
        int eo = e0 + 8 * lg;
        short8 a_h[2], a_l[2];
        #pragma unroll
        for (int m = 0; m < 2; ++m) {
            size_t off = base + (size_t)(ar0 + m * 16) * 256 + eo;
            a_h[m] = *reinterpret_cast<const short8*>(Ah + off);
            a_l[m] = *reinterpret_cast<const short8*>(Al + off);
        }
        size_t boff = base + (size_t)br * 256 + eo;     // symmetric: row == col
        short8 b_h = *reinterpret_cast<const short8*>(Bh + boff);
        short8 b_l = *reinterpret_cast<const short8*>(Bl + boff);
        #pragma unroll
        for (int m = 0; m < 2; ++m) {
            acc[m] = __builtin_amdgcn_mfma_f32_16x16x32_bf16(a_h[m], b_h, acc[m], 0, 0, 0);
            acc[m] = __builtin_amdgcn_mfma_f32_16x16x32_bf16(a_h[m], b_l, acc[m], 0, 0, 0);
            acc[m] = __builtin_amdgcn_mfma_f32_16x16x32_bf16(a_l[m], b_h, acc[m], 0, 0, 0);
        }
    }
    #pragma unroll
    for (int m = 0; m < 2; ++m)
        #pragma unroll
        for (int r = 0; r < 4; ++r) {
            int row = i0 + m * 16 + 4 * lg + r;   // C: col=lane&15, row=(lane>>4)*4+r
            int col = j0 + w * 16 + l15;
            float v = acc[m][r];
            if (mode2i) v = ((row == col) ? 2.f : 0.f) - v;
            unsigned short h, l; split2(v, h, l);
            size_t off = base + (size_t)row * 256 + col;
            Ch[off] = h; Cl[off] = l;
        }
}

// ---------- negatives pre-split (once) + min-buffer init ----------
__global__ __launch_bounds__(256) void knegsplit(const float* __restrict__ negs,
                                                 unsigned short* __restrict__ NH,
                                                 unsigned short* __restrict__ NL,
                                                 unsigned* __restrict__ mina,
                                                 unsigned* __restrict__ minv) {
    size_t i8 = ((size_t)blockIdx.x * 256 + threadIdx.x) * 8;
    f32x4 v0 = *reinterpret_cast<const f32x4*>(negs + i8);
    f32x4 v1 = *reinterpret_cast<const f32x4*>(negs + i8 + 4);
    short8 h, l;
    #pragma unroll
    for (int j = 0; j < 4; ++j) {
        unsigned short hh, ll;
        split2(v0[j], hh, ll); h[j] = (short)hh; l[j] = (short)ll;
        split2(v1[j], hh, ll); h[4 + j] = (short)hh; l[4 + j] = (short)ll;
    }
    *reinterpret_cast<short8*>(NH + i8) = h;
    *reinterpret_cast<short8*>(NL + i8) = l;
    if (blockIdx.x == 0) {
        mina[threadIdx.x] = 0x7f800000u; minv[threadIdx.x] = 0x7f800000u;
    }
}

// ---------- per (b,k): PA row (split), pAp, dpos2 ----------
__global__ __launch_bounds__(256) void k2(const float* __restrict__ Z1, const float* __restrict__ Z2,
                                          const int* __restrict__ match,
                                          const unsigned short* __restrict__ AH,
                                          const unsigned short* __restrict__ AL,
                                          float* __restrict__ ws) {
    int bk = blockIdx.x; int b = bk >> 4; int t = threadIdx.x;
    const unsigned short* Ah = AH + (size_t)b * 65536;
    const unsigned short* Al = AL + (size_t)b * 65536;
    __shared__ float z[DD], df[DD];
    __shared__ float red[256];
    int m = match[bk];
    float zv = Z1[(size_t)bk * DD + t];
    float qv = Z2[((size_t)b * KK + m) * DD + t];
    z[t] = zv; df[t] = zv - qv;
    __syncthreads();
    float pa = 0.f, da = 0.f;
    for (int e = 0; e < DD; ++e) {
        float Ae = bf_tof(Ah[(size_t)e * 256 + t]) + bf_tof(Al[(size_t)e * 256 + t]);
        pa = fmaf(z[e], Ae, pa);
        da = fmaf(df[e], Ae, da);
    }
    unsigned short ph, pl; split2(pa, ph, pl);
    ((unsigned short*)(ws + OFF_PA_H))[(size_t)bk * 256 + t] = ph;   // PA[b][k][e]
    ((unsigned short*)(ws + OFF_PA_L))[(size_t)bk * 256 + t] = pl;
    float dfv = df[t];
    red[t] = pa * zv; __syncthreads();
    for (int s = 128; s > 0; s >>= 1) { if (t < s) red[t] += red[t + s]; __syncthreads(); }
    float pAp = red[0]; __syncthreads();
    red[t] = da * dfv; __syncthreads();
    for (int s = 128; s > 0; s >>= 1) { if (t < s) red[t] += red[t + s]; __syncthreads(); }
    if (t == 0) {
        ws[OFF_PAP + bk]   = pAp;
        ws[OFF_DPOS2 + bk] = fmaxf(red[0], EPS_);
    }
}

// ---------- main kernel: LDS-staged, software-pipelined MFMA  N @ [A | PA^T] + fused mins ----------
// 512 thr = 8 waves (wm x wf = 2x4); n-tile 128; f-tiles 17 (16 A + 1 PA), round-robin F = ff*4+wf.
__global__ __launch_bounds__(512, 4) void k3(const float* __restrict__ negs,
                                             const unsigned short* __restrict__ Ahi,
                                             const unsigned short* __restrict__ Alo,
                                             const unsigned short* __restrict__ PAh,
                                             const unsigned short* __restrict__ PAl,
                                             const unsigned short* __restrict__ NH,
                                             const unsigned short* __restrict__ NL,
                                             const float* __restrict__ pap,
                                             const float* __restrict__ dpos2,
                                             unsigned* __restrict__ mina,
                                             unsigned* __restrict__ minv) {
    __shared__ float smemf[12032];                     // 48.1 KB (staging 43.5 KB / epilogue 48.1 KB union)
    unsigned short* Bh = (unsigned short*)smemf;       // [272][40] bf16-hi
    unsigned short* Bl = Bh + 10880;                   // [272][40] bf16-lo

    int lin = blockIdx.x;
    int b  = (lin & 7) * 2 + ((lin >> 3) & 1);         // XCD-aware: 2 b-values per XCD (A stays L2-hot)
    int n0 = (lin >> 4) * 128;
    int t = threadIdx.x, lane = t & 63, wid = t >> 6;
    int wm = wid & 1, wf = wid >> 1;
    int l15 = lane & 15, lg = lane >> 4;
    const unsigned short* Ab  = Ahi + (size_t)b * 65536;
    const unsigned short* Al_ = Alo + (size_t)b * 65536;
    const unsigned short* Ph  = PAh + (size_t)b * 4096;
    const unsigned short* Pl  = PAl + (size_t)b * 4096;
    const unsigned short* Nh  = NH + (size_t)n0 * 256;
    const unsigned short* Nl  = NL + (size_t)n0 * 256;

    int sr = t >> 1, sh_ = t & 1;                      // staging: A row, 32B half
    bool hasPA = (t < 32);
    int pr = 256 + (t >> 1);

    short8 stA_h[2], stA_l[2], stP_h[2], stP_l[2];
    short8 af_h[2][4], af_l[2][4];
    f32x4 acc[4][5] = {};

    auto loadStage = [&](int c) {
        int eo = c * 32 + sh_ * 16;
        const unsigned short* gh = Ab + (size_t)sr * 256 + eo;
        const unsigned short* gl = Al_ + (size_t)sr * 256 + eo;
        stA_h[0] = *reinterpret_cast<const short8*>(gh);
        stA_h[1] = *reinterpret_cast<const short8*>(gh + 8);
        stA_l[0] = *reinterpret_cast<const short8*>(gl);
        stA_l[1] = *reinterpret_cast<const short8*>(gl + 8);
        if (hasPA) {
            const unsigned short* qh = Ph + (size_t)(t >> 1) * 256 + eo;
            const unsigned short* ql = Pl + (size_t)(t >> 1) * 256 + eo;
            stP_h[0] = *reinterpret_cast<const short8*>(qh);
            stP_h[1] = *reinterpret_cast<const short8*>(qh + 8);
            stP_l[0] = *reinterpret_cast<const short8*>(ql);
            stP_l[1] = *reinterpret_cast<const short8*>(ql + 8);
        }
    };
    auto writeStage = [&]() {
        unsigned short* dh = Bh + sr * 40 + sh_ * 16;
        unsigned short* dl = Bl + sr * 40 + sh_ * 16;
        *reinterpret_cast<short8*>(dh)     = stA_h[0];
        *reinterpret_cast<short8*>(dh + 8) = stA_h[1];
        *reinterpret_cast<short8*>(dl)     = stA_l[0];
        *reinterpret_cast<short8*>(dl + 8) = stA_l[1];
        if (hasPA) {
            unsigned short* eh = Bh + pr * 40 + sh_ * 16;
            unsigned short* el = Bl + pr * 40 + sh_ * 16;
            *reinterpret_cast<short8*>(eh)     = stP_h[0];
            *reinterpret_cast<short8*>(eh + 8) = stP_h[1];
            *reinterpret_cast<short8*>(el)     = stP_l[0];
            *reinterpret_cast<short8*>(el + 8) = stP_l[1];
        }
    };

    // prologue
    loadStage(0);
    {   // a-frags chunk 0 -> buffer 0
        int eo = 8 * lg;
        #pragma unroll
        for (int m = 0; m < 4; ++m) {
            size_t off = (size_t)(wm * 64 + m * 16 + l15) * 256 + eo;
            af_h[0][m] = *reinterpret_cast<const short8*>(Nh + off);
            af_l[0][m] = *reinterpret_cast<const short8*>(Nl + off);
        }
    }
    writeStage();
    __syncthreads();

    #pragma unroll
    for (int c = 0; c < 8; ++c) {
        const int cur = c & 1, nxt = cur ^ 1;
        if (c < 7) {
            loadStage(c + 1);                          // global -> regs (hidden under MFMA)
            int eo = (c + 1) * 32 + 8 * lg;
            #pragma unroll
            for (int m = 0; m < 4; ++m) {
                size_t off = (size_t)(wm * 64 + m * 16 + l15) * 256 + eo;
                af_h[nxt][m] = *reinterpret_cast<const short8*>(Nh + off);
                af_l[nxt][m] = *reinterpret_cast<const short8*>(Nl + off);
            }
        }
        #pragma unroll
        for (int ff = 0; ff < 5; ++ff) {
            if (ff == 4 && wf != 0) continue;          // F >= 17
            int frow = (ff * 4 + wf) * 16 + l15;
            short8 bh = *reinterpret_cast<const short8*>(Bh + frow * 40 + 8 * lg);
            short8 bl = *reinterpret_cast<const short8*>(Bl + frow * 40 + 8 * lg);
            #pragma unroll
            for (int m = 0; m < 4; ++m) {
                acc[m][ff] = __builtin_amdgcn_mfma_f32_16x16x32_bf16(af_h[cur][m], bh, acc[m][ff], 0, 0, 0);
                acc[m][ff] = __builtin_amdgcn_mfma_f32_16x16x32_bf16(af_h[cur][m], bl, acc[m][ff], 0, 0, 0);
                acc[m][ff] = __builtin_amdgcn_mfma_f32_16x16x32_bf16(af_l[cur][m], bh, acc[m][ff], 0, 0, 0);
            }
        }
        __syncthreads();                               // all waves done reading chunk c
        if (c < 7) writeStage();                       // stage chunk c+1
        __syncthreads();
    }

    // ---- epilogue: nAn = rowsum(Y .* N) over F<16; pAn = acc[m][4] on wf==0 (F=16) ----
    float* pAn_l = smemf;            // [128][17]
    float* nAnp  = smemf + 2176;     // [4][128][17]
    float* nAn_l = smemf + 10880;    // [128]
    float* reda  = smemf + 11008;    // [512]
    float* redv  = smemf + 11520;    // [512]

    #pragma unroll
    for (int m = 0; m < 4; ++m) {
        #pragma unroll
        for (int r = 0; r < 4; ++r) {
            int nl = wm * 64 + m * 16 + 4 * lg + r;    // C: row=(lane>>4)*4+r
            int n  = n0 + nl;
            float s = 0.f;
            #pragma unroll
            for (int ff = 0; ff < 4; ++ff) {
                int F = ff * 4 + wf;                   // < 16
                float w = negs[(size_t)n * 256 + F * 16 + l15];
                s = fmaf(acc[m][ff][r], w, s);
            }
            nAnp[(wf * 128 + nl) * 17 + l15] = s;
            if (wf == 0) pAn_l[nl * 17 + l15] = acc[m][4][r];   // f = 256+l15 => k
        }
    }
    __syncthreads();
    if (t < 128) {
        float s = 0.f;
        #pragma unroll
        for (int wfi = 0; wfi < 4; ++wfi)
            #pragma unroll
            for (int x = 0; x < 16; ++x) s += nAnp[(wfi * 128 + t) * 17 + x];
        nAn_l[t] = s;
    }
    __syncthreads();
    int tx = t & 15, ty = t >> 4;                      // ty 0..31
    float pApk = pap[b * 16 + tx];
    float dp2  = dpos2[b * 16 + tx];
    float mn_a = __uint_as_float(0x7f800000u), mn_v = mn_a;
    #pragma unroll
    for (int ii = 0; ii < 4; ++ii) {
        int n = ty * 4 + ii;
        float d2v = pApk - 2.f * pAn_l[n * 17 + tx] + nAn_l[n];
        float cc = fmaxf(d2v, EPS_);
        mn_a = fminf(mn_a, cc);
        if (cc > dp2) mn_v = fminf(mn_v, cc);
    }
    reda[ty * 16 + tx] = mn_a; redv[ty * 16 + tx] = mn_v;
    __syncthreads();
    if (ty == 0) {
        float ra = reda[tx], rv = redv[tx];
        #pragma unroll
        for (int y = 1; y < 32; ++y) {
            ra = fminf(ra, reda[y * 16 + tx]);
            rv = fminf(rv, redv[y * 16 + tx]);
        }
        atomicMin(&mina[b * 16 + tx], __float_as_uint(ra));
        atomicMin(&minv[b * 16 + tx], __float_as_uint(rv));
    }
}

// ---------- final loss ----------
__global__ __launch_bounds__(256) void k5(const float* __restrict__ dpos2,
                                          const unsigned* __restrict__ mina,
                                          const unsigned* __restrict__ minv,
                                          float* __restrict__ out) {
    int t = threadIdx.x;
    __shared__ float red[256];
    float dp = sqrtf(dpos2[t]);
    unsigned mv = minv[t], ma = mina[t];
    unsigned sel = (mv < 0x7f800000u) ? mv : ma;
    float dn = sqrtf(__uint_as_float(sel));
    red[t] = fmaxf(dp - dn + ALPHA_, 0.f);
    __syncthreads();
    for (int s = 128; s > 0; s >>= 1) { if (t < s) red[t] += red[t + s]; __syncthreads(); }
    if (t == 0) out[0] = red[0] * (1.f / 256.f);
}

extern "C" void kernel_launch(void* const* d_in, const int* in_sizes, int n_in,
                              void* d_out, int out_size, void* d_ws, size_t ws_size,
                              hipStream_t stream) {
    (void)in_sizes; (void)n_in; (void)out_size; (void)ws_size;
    const float* Z1   = (const float*)d_in[0];
    const float* Z2   = (const float*)d_in[1];
    const int*   mat  = (const int*)d_in[2];
    const float* negs = (const float*)d_in[3];
    const float* Sig  = (const float*)d_in[4];
    float* ws = (float*)d_ws;
    unsigned short* S_H  = (unsigned short*)(ws + OFF_S_H);
    unsigned short* S_L  = (unsigned short*)(ws + OFF_S_L);
    unsigned short* XA_H = (unsigned short*)(ws + OFF_XA_H);
    unsigned short* XA_L = (unsigned short*)(ws + OFF_XA_L);
    unsigned short* XB_H = (unsigned short*)(ws + OFF_XB_H);
    unsigned short* XB_L = (unsigned short*)(ws + OFF_XB_L);
    unsigned short* T_H  = (unsigned short*)(ws + OFF_T_H);
    unsigned short* T_L  = (unsigned short*)(ws + OFF_T_L);
    unsigned short* PA_H = (unsigned short*)(ws + OFF_PA_H);
    unsigned short* PA_L = (unsigned short*)(ws + OFF_PA_L);
    unsigned short* NH   = (unsigned short*)(ws + OFF_NH);
    unsigned short* NL   = (unsigned short*)(ws + OFF_NL);
    unsigned* mina = (unsigned*)(ws + OFF_MINA);
    unsigned* minv = (unsigned*)(ws + OFF_MINV);
    float* out = (float*)d_out;

    kbound<<<BB, 256, 0, stream>>>(Sig, ws);
    ksplitS<<<4096, 256, 0, stream>>>(Sig, S_H, S_L, BB * DD * DD);
    kinitx<<<4096, 256, 0, stream>>>(Sig, ws);

    unsigned short* pah = XA_H; unsigned short* pal = XA_L;
    unsigned short* pbh = XB_H; unsigned short* pbl = XB_L;
    for (int it = 0; it < ITERS; ++it) {
        gemm_mfma<<<dim3(32, BB), 256, 0, stream>>>(S_H, S_L, pah, pal, T_H, T_L, 1);   // T = 2I - S@X
        gemm_mfma<<<dim3(32, BB), 256, 0, stream>>>(pah, pal, T_H, T_L, pbh, pbl, 0);   // X' = X@T
        unsigned short* th = pah; pah = pbh; pbh = th;
        unsigned short* tl = pal; pal = pbl; pbl = tl;
    }
    // ITERS=5 (odd) => final split inverse in XB_H/XB_L (== pah/pal); XA/T/S now dead

    knegsplit<<<NNEG * DD / 8 / 256, 256, 0, stream>>>(negs, NH, NL, mina, minv);
    k2<<<BB * KK, 256, 0, stream>>>(Z1, Z2, mat, pah, pal, ws);
    k3<<<BB * NNEG / 128, 512, 0, stream>>>(negs, pah, pal, PA_H, PA_L, NH, NL,
                                            ws + OFF_PAP, ws + OFF_DPOS2, mina, minv);
    k5<<<1, 256, 0, stream>>>(ws + OFF_DPOS2, mina, minv, out);
}

// Round 5
// 459.659 us; speedup vs baseline: 1.7358x; 1.7358x over previous
//
#include <hip/hip_runtime.h>
#include <hip/hip_bf16.h>

#define ALPHA_ 0.2f
#define EPS_ 1e-12f

typedef short short8 __attribute__((ext_vector_type(8)));
typedef float f32x4 __attribute__((ext_vector_type(4)));

constexpr int BB = 16, KK = 16, DD = 256, NNEG = 16384;
constexpr int ITERS = 5;   // Newton-Schulz iterations (odd => final lands in XB)

// ---- workspace layout (float offsets) ---- total 5,309,440 floats <= proven 21.2 MB
constexpr size_t OFF_C01   = 0;         // 32 floats (dead after kinitx)
constexpr size_t OFF_NL    = 0;         // 2M floats: neg-lo (overlays C01+XA after Newton)
constexpr size_t OFF_XA_H  = 1048576;
constexpr size_t OFF_XA_L  = 1572864;
constexpr size_t OFF_XB_H  = 2097152;   // FINAL A hi
constexpr size_t OFF_XB_L  = 2621440;   // FINAL A lo
constexpr size_t OFF_NH    = 3145728;   // 2M floats: neg-hi (overlays T+S after Newton)
constexpr size_t OFF_T_H   = 3145728;
constexpr size_t OFF_T_L   = 3670016;
constexpr size_t OFF_S_H   = 4194304;
constexpr size_t OFF_S_L   = 4718592;
constexpr size_t OFF_PA_H  = 5242880;   // 65536 ushorts
constexpr size_t OFF_PA_L  = 5275648;
constexpr size_t OFF_PAP   = 5308416;
constexpr size_t OFF_DPOS2 = 5308672;
constexpr size_t OFF_MINA  = 5308928;
constexpr size_t OFF_MINV  = 5309184;

// ---------- bf16 split helpers (RNE) ----------
__device__ inline unsigned short bf_hi(float x) {
    unsigned u = __float_as_uint(x);
    return (unsigned short)((u + 0x7fffu + ((u >> 16) & 1u)) >> 16);
}
__device__ inline float bf_tof(unsigned short h) { return __uint_as_float(((unsigned)h) << 16); }
__device__ inline void split2(float x, unsigned short& h, unsigned short& l) {
    h = bf_hi(x); l = bf_hi(x - bf_tof(h));
}

// ---------- Gershgorin bound -> degree-2 minimax init: X0 = c0*I + c1*S ----------
__global__ __launch_bounds__(256) void kbound(const float* __restrict__ Sig, float* __restrict__ ws) {
    int b = blockIdx.x, t = threadIdx.x;
    const float* S = Sig + (size_t)b * 65536;
    __shared__ float red[256];
    float cs = 0.f;
    for (int i = 0; i < 256; ++i) cs += fabsf(S[(size_t)i * 256 + t]);
    red[t] = cs; __syncthreads();
    for (int s = 128; s > 0; s >>= 1) { if (t < s) red[t] = fmaxf(red[t], red[t + s]); __syncthreads(); }
    if (t == 0) {
        float G = red[0];                       // >= lambda_max; lambda_min >= 1
        float c1 = -2.f / (G + (G + 1.f) * (G + 1.f) * 0.25f);
        float c0 = -c1 * (G + 1.f);
        ws[OFF_C01 + b] = c0; ws[OFF_C01 + 16 + b] = c1;
    }
}

// ---------- fp32 -> bf16 hi/lo split for Sigma ----------
__global__ __launch_bounds__(256) void ksplitS(const float* __restrict__ in,
                                               unsigned short* __restrict__ h,
                                               unsigned short* __restrict__ l, int n) {
    int i = blockIdx.x * 256 + threadIdx.x;
    if (i < n) { unsigned short hh, ll; split2(in[i], hh, ll); h[i] = hh; l[i] = ll; }
}

// ---------- X0 = c0*I + c1*S (split) ----------
__global__ __launch_bounds__(256) void kinitx(const float* __restrict__ Sig, float* __restrict__ ws) {
    int idx = blockIdx.x * 256 + threadIdx.x;
    int b = idx >> 16, rc = idx & 65535;
    int r = rc >> 8, c = rc & 255;
    float c0 = ws[OFF_C01 + b], c1 = ws[OFF_C01 + 16 + b];
    float v = c1 * Sig[idx] + ((r == c) ? c0 : 0.f);
    unsigned short h, l; split2(v, h, l);
    ((unsigned short*)(ws + OFF_XA_H))[idx] = h;
    ((unsigned short*)(ws + OFF_XA_L))[idx] = l;
}

// ---------- batched 256x256 MFMA split GEMM, 32x64 tiles, 512 blocks (2/CU) ----------
__global__ __launch_bounds__(256) void gemm_mfma(const unsigned short* __restrict__ Ah,
                                                 const unsigned short* __restrict__ Al,
                                                 const unsigned short* __restrict__ Bh,
                                                 const unsigned short* __restrict__ Bl,
                                                 unsigned short* __restrict__ Ch,
                                                 unsigned short* __restrict__ Cl, int mode2i) {
    int b = blockIdx.y;
    int i0 = (blockIdx.x >> 2) * 32, j0 = (blockIdx.x & 3) * 64;
    size_t base = (size_t)b * 65536;
    int t = threadIdx.x, lane = t & 63, w = t >> 6;
    int l15 = lane & 15, lg = lane >> 4;
    f32x4 acc[2] = {};
    int ar0 = i0 + l15;
    int br  = j0 + w * 16 + l15;
    #pragma unroll
    for (int e0 = 0; e0 < 256; e0 += 32) {
        int eo = e0 + 8 * lg;
        short8 a_h[2], a_l[2];
        #pragma unroll
        for (int m = 0; m < 2; ++m) {
            size_t off = base + (size_t)(ar0 + m * 16) * 256 + eo;
            a_h[m] = *reinterpret_cast<const short8*>(Ah + off);
            a_l[m] = *reinterpret_cast<const short8*>(Al + off);
        }
        size_t boff = base + (size_t)br * 256 + eo;     // symmetric: row == col
        short8 b_h = *reinterpret_cast<const short8*>(Bh + boff);
        short8 b_l = *reinterpret_cast<const short8*>(Bl + boff);
        #pragma unroll
        for (int m = 0; m < 2; ++m) {
            acc[m] = __builtin_amdgcn_mfma_f32_16x16x32_bf16(a_h[m], b_h, acc[m], 0, 0, 0);
            acc[m] = __builtin_amdgcn_mfma_f32_16x16x32_bf16(a_h[m], b_l, acc[m], 0, 0, 0);
            acc[m] = __builtin_amdgcn_mfma_f32_16x16x32_bf16(a_l[m], b_h, acc[m], 0, 0, 0);
        }
    }
    #pragma unroll
    for (int m = 0; m < 2; ++m)
        #pragma unroll
        for (int r = 0; r < 4; ++r) {
            int row = i0 + m * 16 + 4 * lg + r;
            int col = j0 + w * 16 + l15;
            float v = acc[m][r];
            if (mode2i) v = ((row == col) ? 2.f : 0.f) - v;
            unsigned short h, l; split2(v, h, l);
            size_t off = base + (size_t)row * 256 + col;
            Ch[off] = h; Cl[off] = l;
        }
}

// ---------- negatives pre-split (once) + min-buffer init ----------
__global__ __launch_bounds__(256) void knegsplit(const float* __restrict__ negs,
                                                 unsigned short* __restrict__ NH,
                                                 unsigned short* __restrict__ NL,
                                                 unsigned* __restrict__ mina,
                                                 unsigned* __restrict__ minv) {
    size_t i8 = ((size_t)blockIdx.x * 256 + threadIdx.x) * 8;
    f32x4 v0 = *reinterpret_cast<const f32x4*>(negs + i8);
    f32x4 v1 = *reinterpret_cast<const f32x4*>(negs + i8 + 4);
    short8 h, l;
    #pragma unroll
    for (int j = 0; j < 4; ++j) {
        unsigned short hh, ll;
        split2(v0[j], hh, ll); h[j] = (short)hh; l[j] = (short)ll;
        split2(v1[j], hh, ll); h[4 + j] = (short)hh; l[4 + j] = (short)ll;
    }
    *reinterpret_cast<short8*>(NH + i8) = h;
    *reinterpret_cast<short8*>(NL + i8) = l;
    if (blockIdx.x == 0) {
        mina[threadIdx.x] = 0x7f800000u; minv[threadIdx.x] = 0x7f800000u;
    }
}

// ---------- per (b,k): PA row (split), pAp, dpos2 ----------
__global__ __launch_bounds__(256) void k2(const float* __restrict__ Z1, const float* __restrict__ Z2,
                                          const int* __restrict__ match,
                                          const unsigned short* __restrict__ AH,
                                          const unsigned short* __restrict__ AL,
                                          float* __restrict__ ws) {
    int bk = blockIdx.x; int b = bk >> 4; int t = threadIdx.x;
    const unsigned short* Ah = AH + (size_t)b * 65536;
    const unsigned short* Al = AL + (size_t)b * 65536;
    __shared__ float z[DD], df[DD];
    __shared__ float red[256];
    int m = match[bk];
    float zv = Z1[(size_t)bk * DD + t];
    float qv = Z2[((size_t)b * KK + m) * DD + t];
    z[t] = zv; df[t] = zv - qv;
    __syncthreads();
    float pa = 0.f, da = 0.f;
    for (int e = 0; e < DD; ++e) {
        float Ae = bf_tof(Ah[(size_t)e * 256 + t]) + bf_tof(Al[(size_t)e * 256 + t]);
        pa = fmaf(z[e], Ae, pa);
        da = fmaf(df[e], Ae, da);
    }
    unsigned short ph, pl; split2(pa, ph, pl);
    ((unsigned short*)(ws + OFF_PA_H))[(size_t)bk * 256 + t] = ph;
    ((unsigned short*)(ws + OFF_PA_L))[(size_t)bk * 256 + t] = pl;
    float dfv = df[t];
    red[t] = pa * zv; __syncthreads();
    for (int s = 128; s > 0; s >>= 1) { if (t < s) red[t] += red[t + s]; __syncthreads(); }
    float pAp = red[0]; __syncthreads();
    red[t] = da * dfv; __syncthreads();
    for (int s = 128; s > 0; s >>= 1) { if (t < s) red[t] += red[t + s]; __syncthreads(); }
    if (t == 0) {
        ws[OFF_PAP + bk]   = pAp;
        ws[OFF_DPOS2 + bk] = fmaxf(red[0], EPS_);
    }
}

// ---------- main kernel: r2 structure + pre-split negatives ----------
// 256 thr = 4 waves (wm x wf = 2x2). n-tile 128, f-range 272 (256 A + 16 PA).
__global__ __launch_bounds__(256, 2) void k3(const float* __restrict__ negs,
                                             const unsigned short* __restrict__ Ahi,
                                             const unsigned short* __restrict__ Alo,
                                             const unsigned short* __restrict__ PAh,
                                             const unsigned short* __restrict__ PAl,
                                             const unsigned short* __restrict__ NH,
                                             const unsigned short* __restrict__ NL,
                                             const float* __restrict__ pap,
                                             const float* __restrict__ dpos2,
                                             unsigned* __restrict__ mina,
                                             unsigned* __restrict__ minv) {
    __shared__ float smem[10880];                      // 43.5 KB
    unsigned short* Bh = (unsigned short*)smem;        // [272][40] bf16-hi (pad 40: 16B-aligned rows)
    unsigned short* Bl = Bh + 272 * 40;

    int lin = blockIdx.x;
    int b  = (lin & 7) * 2 + ((lin >> 3) & 1);         // XCD-aware: 2 b-values per XCD
    int n0 = (lin >> 4) * 128;
    int t = threadIdx.x, lane = t & 63, wid = t >> 6;
    int wm = wid & 1, wf = wid >> 1;
    int l15 = lane & 15, lg = lane >> 4;
    const unsigned short* Ab  = Ahi + (size_t)b * 65536;
    const unsigned short* Al_ = Alo + (size_t)b * 65536;
    const unsigned short* Ph  = PAh + (size_t)b * 4096;
    const unsigned short* Pl  = PAl + (size_t)b * 4096;
    const unsigned short* Nh  = NH + (size_t)n0 * 256;
    const unsigned short* Nl  = NL + (size_t)n0 * 256;

    f32x4 acc[4][9] = {};
    for (int e0 = 0; e0 < 256; e0 += 32) {
        // a-frags for THIS chunk (global, pre-split bf16) — issued before the barrier
        short8 ah[4], al[4];
        {
            int eo = e0 + 8 * lg;
            #pragma unroll
            for (int m = 0; m < 4; ++m) {
                size_t off = (size_t)(wm * 64 + m * 16 + l15) * 256 + eo;
                ah[m] = *reinterpret_cast<const short8*>(Nh + off);
                al[m] = *reinterpret_cast<const short8*>(Nl + off);
            }
        }
        __syncthreads();
        {   // stage B^T chunk: rows 0..255 = A rows (symmetric), 256..271 = PA rows
            const unsigned short* sh = Ab + (size_t)t * 256 + e0;
            const unsigned short* sl = Al_ + (size_t)t * 256 + e0;
            #pragma unroll
            for (int j = 0; j < 4; ++j) {
                *reinterpret_cast<short8*>(&Bh[t * 40 + j * 8]) = *reinterpret_cast<const short8*>(sh + j * 8);
                *reinterpret_cast<short8*>(&Bl[t * 40 + j * 8]) = *reinterpret_cast<const short8*>(sl + j * 8);
            }
            if (t < 16) {
                int r2 = 256 + t;
                const unsigned short* ph = Ph + (size_t)t * 256 + e0;
                const unsigned short* pl = Pl + (size_t)t * 256 + e0;
                #pragma unroll
                for (int j = 0; j < 4; ++j) {
                    *reinterpret_cast<short8*>(&Bh[r2 * 40 + j * 8]) = *reinterpret_cast<const short8*>(ph + j * 8);
                    *reinterpret_cast<short8*>(&Bl[r2 * 40 + j * 8]) = *reinterpret_cast<const short8*>(pl + j * 8);
                }
            }
        }
        __syncthreads();
        #pragma unroll
        for (int ff = 0; ff < 9; ++ff) {
            if (ff == 8 && wf == 1) continue;          // f >= 272
            int frow = wf * 144 + ff * 16 + l15;
            short8 bh = *reinterpret_cast<const short8*>(&Bh[frow * 40 + 8 * lg]);
            short8 bl = *reinterpret_cast<const short8*>(&Bl[frow * 40 + 8 * lg]);
            #pragma unroll
            for (int m = 0; m < 4; ++m) {
                acc[m][ff] = __builtin_amdgcn_mfma_f32_16x16x32_bf16(ah[m], bh, acc[m][ff], 0, 0, 0);
                acc[m][ff] = __builtin_amdgcn_mfma_f32_16x16x32_bf16(ah[m], bl, acc[m][ff], 0, 0, 0);
                acc[m][ff] = __builtin_amdgcn_mfma_f32_16x16x32_bf16(al[m], bh, acc[m][ff], 0, 0, 0);
            }
        }
    }
    __syncthreads();
    // ---- epilogue: nAn = rowsum(Y .* N) over f<256; pAn from PA frag (wf1, ff=7) ----
    float* pAn_l = smem;            // [128][17]
    float* nAnp  = smem + 2176;     // [2][128][17]
    float* nAn_l = smem + 6528;     // [128]
    float* reda  = smem + 6656;     // [256]
    float* redv  = smem + 6912;     // [256]

    #pragma unroll
    for (int m = 0; m < 4; ++m) {
        #pragma unroll
        for (int r = 0; r < 4; ++r) {
            int nl = wm * 64 + m * 16 + 4 * lg + r;     // C: row=(lane>>4)*4+r
            int n  = n0 + nl;
            float s = 0.f;
            #pragma unroll
            for (int ff = 0; ff < 9; ++ff) {
                int fb = wf * 144 + ff * 16;
                if (fb < 256) {
                    float w = negs[(size_t)n * 256 + fb + l15];
                    s = fmaf(acc[m][ff][r], w, s);
                }
            }
            nAnp[(wf * 128 + nl) * 17 + l15] = s;
            if (wf == 1) pAn_l[nl * 17 + l15] = acc[m][7][r];
        }
    }
    __syncthreads();
    if (t < 128) {
        float s = 0.f;
        #pragma unroll
        for (int x = 0; x < 16; ++x) s += nAnp[t * 17 + x] + nAnp[(128 + t) * 17 + x];
        nAn_l[t] = s;
    }
    __syncthreads();
    int tx = t & 15, ty = t >> 4;
    float pApk = pap[b * 16 + tx];
    float dp2  = dpos2[b * 16 + tx];
    float mn_a = __uint_as_float(0x7f800000u), mn_v = mn_a;
    #pragma unroll
    for (int ii = 0; ii < 8; ++ii) {
        int n = ty * 8 + ii;
        float d2v = pApk - 2.f * pAn_l[n * 17 + tx] + nAn_l[n];
        float c = fmaxf(d2v, EPS_);
        mn_a = fminf(mn_a, c);
        if (c > dp2) mn_v = fminf(mn_v, c);
    }
    reda[ty * 16 + tx] = mn_a; redv[ty * 16 + tx] = mn_v;
    __syncthreads();
    if (ty == 0) {
        float ra = reda[tx], rv = redv[tx];
        #pragma unroll
        for (int y = 1; y < 16; ++y) {
            ra = fminf(ra, reda[y * 16 + tx]);
            rv = fminf(rv, redv[y * 16 + tx]);
        }
        atomicMin(&mina[b * 16 + tx], __float_as_uint(ra));
        atomicMin(&minv[b * 16 + tx], __float_as_uint(rv));
    }
}

// ---------- final loss ----------
__global__ __launch_bounds__(256) void k5(const float* __restrict__ dpos2,
                                          const unsigned* __restrict__ mina,
                                          const unsigned* __restrict__ minv,
                                          float* __restrict__ out) {
    int t = threadIdx.x;
    __shared__ float red[256];
    float dp = sqrtf(dpos2[t]);
    unsigned mv = minv[t], ma = mina[t];
    unsigned sel = (mv < 0x7f800000u) ? mv : ma;
    float dn = sqrtf(__uint_as_float(sel));
    red[t] = fmaxf(dp - dn + ALPHA_, 0.f);
    __syncthreads();
    for (int s = 128; s > 0; s >>= 1) { if (t < s) red[t] += red[t + s]; __syncthreads(); }
    if (t == 0) out[0] = red[0] * (1.f / 256.f);
}

extern "C" void kernel_launch(void* const* d_in, const int* in_sizes, int n_in,
                              void* d_out, int out_size, void* d_ws, size_t ws_size,
                              hipStream_t stream) {
    (void)in_sizes; (void)n_in; (void)out_size; (void)ws_size;
    const float* Z1   = (const float*)d_in[0];
    const float* Z2   = (const float*)d_in[1];
    const int*   mat  = (const int*)d_in[2];
    const float* negs = (const float*)d_in[3];
    const float* Sig  = (const float*)d_in[4];
    float* ws = (float*)d_ws;
    unsigned short* S_H  = (unsigned short*)(ws + OFF_S_H);
    unsigned short* S_L  = (unsigned short*)(ws + OFF_S_L);
    unsigned short* XA_H = (unsigned short*)(ws + OFF_XA_H);
    unsigned short* XA_L = (unsigned short*)(ws + OFF_XA_L);
    unsigned short* XB_H = (unsigned short*)(ws + OFF_XB_H);
    unsigned short* XB_L = (unsigned short*)(ws + OFF_XB_L);
    unsigned short* T_H  = (unsigned short*)(ws + OFF_T_H);
    unsigned short* T_L  = (unsigned short*)(ws + OFF_T_L);
    unsigned short* PA_H = (unsigned short*)(ws + OFF_PA_H);
    unsigned short* PA_L = (unsigned short*)(ws + OFF_PA_L);
    unsigned short* NH   = (unsigned short*)(ws + OFF_NH);
    unsigned short* NL   = (unsigned short*)(ws + OFF_NL);
    unsigned* mina = (unsigned*)(ws + OFF_MINA);
    unsigned* minv = (unsigned*)(ws + OFF_MINV);
    float* out = (float*)d_out;

    kbound<<<BB, 256, 0, stream>>>(Sig, ws);
    ksplitS<<<4096, 256, 0, stream>>>(Sig, S_H, S_L, BB * DD * DD);
    kinitx<<<4096, 256, 0, stream>>>(Sig, ws);

    unsigned short* pah = XA_H; unsigned short* pal = XA_L;
    unsigned short* pbh = XB_H; unsigned short* pbl = XB_L;
    for (int it = 0; it < ITERS; ++it) {
        gemm_mfma<<<dim3(32, BB), 256, 0, stream>>>(S_H, S_L, pah, pal, T_H, T_L, 1);   // T = 2I - S@X
        gemm_mfma<<<dim3(32, BB), 256, 0, stream>>>(pah, pal, T_H, T_L, pbh, pbl, 0);   // X' = X@T
        unsigned short* th = pah; pah = pbh; pbh = th;
        unsigned short* tl = pal; pal = pbl; pbl = tl;
    }
    // ITERS=5 (odd) => final split inverse in XB_H/XB_L (== pah/pal); XA/T/S now dead

    knegsplit<<<NNEG * DD / 8 / 256, 256, 0, stream>>>(negs, NH, NL, mina, minv);
    k2<<<BB * KK, 256, 0, stream>>>(Z1, Z2, mat, pah, pal, ws);
    k3<<<BB * NNEG / 128, 256, 0, stream>>>(negs, pah, pal, PA_H, PA_L, NH, NL,
                                            ws + OFF_PAP, ws + OFF_DPOS2, mina, minv);
    k5<<<1, 256, 0, stream>>>(ws + OFF_DPOS2, mina, minv, out);
}

// Round 6
// 419.667 us; speedup vs baseline: 1.9012x; 1.0953x over previous
//
#include <hip/hip_runtime.h>
#include <hip/hip_bf16.h>

#define ALPHA_ 0.2f
#define EPS_ 1e-12f

typedef short short8 __attribute__((ext_vector_type(8)));
typedef float f32x4 __attribute__((ext_vector_type(4)));

constexpr int BB = 16, KK = 16, DD = 256, NNEG = 16384;
constexpr int ITERS = 5;   // Newton-Schulz iterations (odd => final lands in XB)

// ---- workspace layout (float offsets) ---- total 5,309,440 floats <= proven 21.2 MB
constexpr size_t OFF_NL    = 0;         // 2M floats: neg-lo (overlays XA after Newton)
constexpr size_t OFF_XA_H  = 1048576;
constexpr size_t OFF_XA_L  = 1572864;
constexpr size_t OFF_XB_H  = 2097152;   // FINAL A hi
constexpr size_t OFF_XB_L  = 2621440;   // FINAL A lo
constexpr size_t OFF_NH    = 3145728;   // 2M floats: neg-hi (overlays T+S after Newton)
constexpr size_t OFF_T_H   = 3145728;
constexpr size_t OFF_T_L   = 3670016;
constexpr size_t OFF_S_H   = 4194304;
constexpr size_t OFF_S_L   = 4718592;
constexpr size_t OFF_PA_H  = 5242880;   // 65536 ushorts
constexpr size_t OFF_PA_L  = 5275648;
constexpr size_t OFF_PAP   = 5308416;
constexpr size_t OFF_DPOS2 = 5308672;
constexpr size_t OFF_MINA  = 5308928;
constexpr size_t OFF_MINV  = 5309184;

// ---------- bf16 split helpers (RNE) ----------
__device__ inline unsigned short bf_hi(float x) {
    unsigned u = __float_as_uint(x);
    return (unsigned short)((u + 0x7fffu + ((u >> 16) & 1u)) >> 16);
}
__device__ inline float bf_tof(unsigned short h) { return __uint_as_float(((unsigned)h) << 16); }
__device__ inline void split2(float x, unsigned short& h, unsigned short& l) {
    h = bf_hi(x); l = bf_hi(x - bf_tof(h));
}

// ---------- fused prep: Gershgorin bound -> X0 = c0*I + c1*S; split S; split X0 ----------
__global__ __launch_bounds__(256) void kprep(const float* __restrict__ Sig, float* __restrict__ ws) {
    int b = blockIdx.x, t = threadIdx.x;
    const float* S = Sig + (size_t)b * 65536;
    __shared__ float red[256];
    __shared__ float cc[2];
    float cs = 0.f;
    for (int i = 0; i < 256; ++i) cs += fabsf(S[(size_t)i * 256 + t]);
    red[t] = cs; __syncthreads();
    for (int s = 128; s > 0; s >>= 1) { if (t < s) red[t] = fmaxf(red[t], red[t + s]); __syncthreads(); }
    if (t == 0) {
        float G = red[0];                       // >= lambda_max; lambda_min >= 1
        float c1 = -2.f / (G + (G + 1.f) * (G + 1.f) * 0.25f);
        cc[0] = -c1 * (G + 1.f); cc[1] = c1;    // c0, c1
    }
    __syncthreads();
    float c0 = cc[0], c1 = cc[1];
    unsigned short* SH = (unsigned short*)(ws + OFF_S_H);
    unsigned short* SL = (unsigned short*)(ws + OFF_S_L);
    unsigned short* XH = (unsigned short*)(ws + OFF_XA_H);
    unsigned short* XL = (unsigned short*)(ws + OFF_XA_L);
    for (int r = 0; r < 256; ++r) {
        size_t idx = (size_t)b * 65536 + (size_t)r * 256 + t;
        float v = Sig[idx];
        unsigned short h, l;
        split2(v, h, l); SH[idx] = h; SL[idx] = l;
        float x0 = c1 * v + ((r == t) ? c0 : 0.f);
        split2(x0, h, l); XH[idx] = h; XL[idx] = l;
    }
}

// ---------- batched 256x256 MFMA split GEMM, 32x64 tiles, 512 blocks (2/CU) ----------
__global__ __launch_bounds__(256) void gemm_mfma(const unsigned short* __restrict__ Ah,
                                                 const unsigned short* __restrict__ Al,
                                                 const unsigned short* __restrict__ Bh,
                                                 const unsigned short* __restrict__ Bl,
                                                 unsigned short* __restrict__ Ch,
                                                 unsigned short* __restrict__ Cl, int mode2i) {
    int b = blockIdx.y;
    int i0 = (blockIdx.x >> 2) * 32, j0 = (blockIdx.x & 3) * 64;
    size_t base = (size_t)b * 65536;
    int t = threadIdx.x, lane = t & 63, w = t >> 6;
    int l15 = lane & 15, lg = lane >> 4;
    f32x4 acc[2] = {};
    int ar0 = i0 + l15;
    int br  = j0 + w * 16 + l15;
    #pragma unroll
    for (int e0 = 0; e0 < 256; e0 += 32) {
        int eo = e0 + 8 * lg;
        short8 a_h[2], a_l[2];
        #pragma unroll
        for (int m = 0; m < 2; ++m) {
            size_t off = base + (size_t)(ar0 + m * 16) * 256 + eo;
            a_h[m] = *reinterpret_cast<const short8*>(Ah + off);
            a_l[m] = *reinterpret_cast<const short8*>(Al + off);
        }
        size_t boff = base + (size_t)br * 256 + eo;     // symmetric: row == col
        short8 b_h = *reinterpret_cast<const short8*>(Bh + boff);
        short8 b_l = *reinterpret_cast<const short8*>(Bl + boff);
        #pragma unroll
        for (int m = 0; m < 2; ++m) {
            acc[m] = __builtin_amdgcn_mfma_f32_16x16x32_bf16(a_h[m], b_h, acc[m], 0, 0, 0);
            acc[m] = __builtin_amdgcn_mfma_f32_16x16x32_bf16(a_h[m], b_l, acc[m], 0, 0, 0);
            acc[m] = __builtin_amdgcn_mfma_f32_16x16x32_bf16(a_l[m], b_h, acc[m], 0, 0, 0);
        }
    }
    #pragma unroll
    for (int m = 0; m < 2; ++m)
        #pragma unroll
        for (int r = 0; r < 4; ++r) {
            int row = i0 + m * 16 + 4 * lg + r;
            int col = j0 + w * 16 + l15;
            float v = acc[m][r];
            if (mode2i) v = ((row == col) ? 2.f : 0.f) - v;
            unsigned short h, l; split2(v, h, l);
            size_t off = base + (size_t)row * 256 + col;
            Ch[off] = h; Cl[off] = l;
        }
}

// ---------- negatives pre-split (once) + min-buffer init ----------
__global__ __launch_bounds__(256) void knegsplit(const float* __restrict__ negs,
                                                 unsigned short* __restrict__ NH,
                                                 unsigned short* __restrict__ NL,
                                                 unsigned* __restrict__ mina,
                                                 unsigned* __restrict__ minv) {
    size_t i8 = ((size_t)blockIdx.x * 256 + threadIdx.x) * 8;
    f32x4 v0 = *reinterpret_cast<const f32x4*>(negs + i8);
    f32x4 v1 = *reinterpret_cast<const f32x4*>(negs + i8 + 4);
    short8 h, l;
    #pragma unroll
    for (int j = 0; j < 4; ++j) {
        unsigned short hh, ll;
        split2(v0[j], hh, ll); h[j] = (short)hh; l[j] = (short)ll;
        split2(v1[j], hh, ll); h[4 + j] = (short)hh; l[4 + j] = (short)ll;
    }
    *reinterpret_cast<short8*>(NH + i8) = h;
    *reinterpret_cast<short8*>(NL + i8) = l;
    if (blockIdx.x == 0) {
        mina[threadIdx.x] = 0x7f800000u; minv[threadIdx.x] = 0x7f800000u;
    }
}

// ---------- per (b,k): PA row (split), pAp, dpos2 ----------
__global__ __launch_bounds__(256) void k2(const float* __restrict__ Z1, const float* __restrict__ Z2,
                                          const int* __restrict__ match,
                                          const unsigned short* __restrict__ AH,
                                          const unsigned short* __restrict__ AL,
                                          float* __restrict__ ws) {
    int bk = blockIdx.x; int b = bk >> 4; int t = threadIdx.x;
    const unsigned short* Ah = AH + (size_t)b * 65536;
    const unsigned short* Al = AL + (size_t)b * 65536;
    __shared__ float z[DD], df[DD];
    __shared__ float red[256];
    int m = match[bk];
    float zv = Z1[(size_t)bk * DD + t];
    float qv = Z2[((size_t)b * KK + m) * DD + t];
    z[t] = zv; df[t] = zv - qv;
    __syncthreads();
    float pa = 0.f, da = 0.f;
    for (int e = 0; e < DD; ++e) {
        float Ae = bf_tof(Ah[(size_t)e * 256 + t]) + bf_tof(Al[(size_t)e * 256 + t]);
        pa = fmaf(z[e], Ae, pa);
        da = fmaf(df[e], Ae, da);
    }
    unsigned short ph, pl; split2(pa, ph, pl);
    ((unsigned short*)(ws + OFF_PA_H))[(size_t)bk * 256 + t] = ph;
    ((unsigned short*)(ws + OFF_PA_L))[(size_t)bk * 256 + t] = pl;
    float dfv = df[t];
    red[t] = pa * zv; __syncthreads();
    for (int s = 128; s > 0; s >>= 1) { if (t < s) red[t] += red[t + s]; __syncthreads(); }
    float pAp = red[0]; __syncthreads();
    red[t] = da * dfv; __syncthreads();
    for (int s = 128; s > 0; s >>= 1) { if (t < s) red[t] += red[t + s]; __syncthreads(); }
    if (t == 0) {
        ws[OFF_PAP + bk]   = pAp;
        ws[OFF_DPOS2 + bk] = fmaxf(red[0], EPS_);
    }
}

// ---------- main kernel: r2 structure + pre-split negatives + XCD-local slices ----------
// Mapping: x=lin&7 (XCD), q=lin>>3, nt=q&15, b=q>>4, n0=(x*16+nt)*128.
// Each XCD owns a 1 MB negative slice (L2-resident) and walks b serially.
__global__ __launch_bounds__(256, 2) void k3(const unsigned short* __restrict__ Ahi,
                                             const unsigned short* __restrict__ Alo,
                                             const unsigned short* __restrict__ PAh,
                                             const unsigned short* __restrict__ PAl,
                                             const unsigned short* __restrict__ NH,
                                             const unsigned short* __restrict__ NL,
                                             const float* __restrict__ pap,
                                             const float* __restrict__ dpos2,
                                             unsigned* __restrict__ mina,
                                             unsigned* __restrict__ minv) {
    __shared__ float smem[10880];                      // 43.5 KB
    unsigned short* Bh = (unsigned short*)smem;        // [272][40] bf16-hi (pad 40: 16B-aligned rows)
    unsigned short* Bl = Bh + 272 * 40;

    int lin = blockIdx.x;
    int x  = lin & 7;
    int q  = lin >> 3;
    int b  = q >> 4;
    int n0 = (x * 16 + (q & 15)) * 128;
    int t = threadIdx.x, lane = t & 63, wid = t >> 6;
    int wm = wid & 1, wf = wid >> 1;
    int l15 = lane & 15, lg = lane >> 4;
    const unsigned short* Ab  = Ahi + (size_t)b * 65536;
    const unsigned short* Al_ = Alo + (size_t)b * 65536;
    const unsigned short* Ph  = PAh + (size_t)b * 4096;
    const unsigned short* Pl  = PAl + (size_t)b * 4096;
    const unsigned short* Nh  = NH + (size_t)n0 * 256;
    const unsigned short* Nl  = NL + (size_t)n0 * 256;

    f32x4 acc[4][9] = {};
    for (int e0 = 0; e0 < 256; e0 += 32) {
        // a-frags for THIS chunk (pre-split bf16, L2-hot) — issued before the barrier
        short8 ah[4], al[4];
        {
            int eo = e0 + 8 * lg;
            #pragma unroll
            for (int m = 0; m < 4; ++m) {
                size_t off = (size_t)(wm * 64 + m * 16 + l15) * 256 + eo;
                ah[m] = *reinterpret_cast<const short8*>(Nh + off);
                al[m] = *reinterpret_cast<const short8*>(Nl + off);
            }
        }
        __syncthreads();
        {   // stage B^T chunk: rows 0..255 = A rows (symmetric), 256..271 = PA rows
            const unsigned short* sh = Ab + (size_t)t * 256 + e0;
            const unsigned short* sl = Al_ + (size_t)t * 256 + e0;
            #pragma unroll
            for (int j = 0; j < 4; ++j) {
                *reinterpret_cast<short8*>(&Bh[t * 40 + j * 8]) = *reinterpret_cast<const short8*>(sh + j * 8);
                *reinterpret_cast<short8*>(&Bl[t * 40 + j * 8]) = *reinterpret_cast<const short8*>(sl + j * 8);
            }
            if (t < 16) {
                int r2 = 256 + t;
                const unsigned short* ph = Ph + (size_t)t * 256 + e0;
                const unsigned short* pl = Pl + (size_t)t * 256 + e0;
                #pragma unroll
                for (int j = 0; j < 4; ++j) {
                    *reinterpret_cast<short8*>(&Bh[r2 * 40 + j * 8]) = *reinterpret_cast<const short8*>(ph + j * 8);
                    *reinterpret_cast<short8*>(&Bl[r2 * 40 + j * 8]) = *reinterpret_cast<const short8*>(pl + j * 8);
                }
            }
        }
        __syncthreads();
        #pragma unroll
        for (int ff = 0; ff < 9; ++ff) {
            if (ff == 8 && wf == 1) continue;          // f >= 272
            int frow = wf * 144 + ff * 16 + l15;
            short8 bh = *reinterpret_cast<const short8*>(&Bh[frow * 40 + 8 * lg]);
            short8 bl = *reinterpret_cast<const short8*>(&Bl[frow * 40 + 8 * lg]);
            #pragma unroll
            for (int m = 0; m < 4; ++m) {
                acc[m][ff] = __builtin_amdgcn_mfma_f32_16x16x32_bf16(ah[m], bh, acc[m][ff], 0, 0, 0);
                acc[m][ff] = __builtin_amdgcn_mfma_f32_16x16x32_bf16(ah[m], bl, acc[m][ff], 0, 0, 0);
                acc[m][ff] = __builtin_amdgcn_mfma_f32_16x16x32_bf16(al[m], bh, acc[m][ff], 0, 0, 0);
            }
        }
    }
    __syncthreads();
    // ---- epilogue: nAn = rowsum(Y .* N) over f<256 (N from hi+lo); pAn from PA frag ----
    float* pAn_l = smem;            // [128][17]
    float* nAnp  = smem + 2176;     // [2][128][17]
    float* nAn_l = smem + 6528;     // [128]
    float* reda  = smem + 6656;     // [256]
    float* redv  = smem + 6912;     // [256]

    #pragma unroll
    for (int m = 0; m < 4; ++m) {
        #pragma unroll
        for (int r = 0; r < 4; ++r) {
            int nl = wm * 64 + m * 16 + 4 * lg + r;     // C: row=(lane>>4)*4+r
            float s = 0.f;
            #pragma unroll
            for (int ff = 0; ff < 9; ++ff) {
                int fb = wf * 144 + ff * 16;
                if (fb < 256) {
                    int ei = nl * 256 + fb + l15;
                    float w = bf_tof(Nh[ei]) + bf_tof(Nl[ei]);
                    s = fmaf(acc[m][ff][r], w, s);
                }
            }
            nAnp[(wf * 128 + nl) * 17 + l15] = s;
            if (wf == 1) pAn_l[nl * 17 + l15] = acc[m][7][r];
        }
    }
    __syncthreads();
    if (t < 128) {
        float s = 0.f;
        #pragma unroll
        for (int xx = 0; xx < 16; ++xx) s += nAnp[t * 17 + xx] + nAnp[(128 + t) * 17 + xx];
        nAn_l[t] = s;
    }
    __syncthreads();
    int tx = t & 15, ty = t >> 4;
    float pApk = pap[b * 16 + tx];
    float dp2  = dpos2[b * 16 + tx];
    float mn_a = __uint_as_float(0x7f800000u), mn_v = mn_a;
    #pragma unroll
    for (int ii = 0; ii < 8; ++ii) {
        int n = ty * 8 + ii;
        float d2v = pApk - 2.f * pAn_l[n * 17 + tx] + nAn_l[n];
        float c = fmaxf(d2v, EPS_);
        mn_a = fminf(mn_a, c);
        if (c > dp2) mn_v = fminf(mn_v, c);
    }
    reda[ty * 16 + tx] = mn_a; redv[ty * 16 + tx] = mn_v;
    __syncthreads();
    if (ty == 0) {
        float ra = reda[tx], rv = redv[tx];
        #pragma unroll
        for (int y = 1; y < 16; ++y) {
            ra = fminf(ra, reda[y * 16 + tx]);
            rv = fminf(rv, redv[y * 16 + tx]);
        }
        atomicMin(&mina[b * 16 + tx], __float_as_uint(ra));
        atomicMin(&minv[b * 16 + tx], __float_as_uint(rv));
    }
}

// ---------- final loss ----------
__global__ __launch_bounds__(256) void k5(const float* __restrict__ dpos2,
                                          const unsigned* __restrict__ mina,
                                          const unsigned* __restrict__ minv,
                                          float* __restrict__ out) {
    int t = threadIdx.x;
    __shared__ float red[256];
    float dp = sqrtf(dpos2[t]);
    unsigned mv = minv[t], ma = mina[t];
    unsigned sel = (mv < 0x7f800000u) ? mv : ma;
    float dn = sqrtf(__uint_as_float(sel));
    red[t] = fmaxf(dp - dn + ALPHA_, 0.f);
    __syncthreads();
    for (int s = 128; s > 0; s >>= 1) { if (t < s) red[t] += red[t + s]; __syncthreads(); }
    if (t == 0) out[0] = red[0] * (1.f / 256.f);
}

extern "C" void kernel_launch(void* const* d_in, const int* in_sizes, int n_in,
                              void* d_out, int out_size, void* d_ws, size_t ws_size,
                              hipStream_t stream) {
    (void)in_sizes; (void)n_in; (void)out_size; (void)ws_size;
    const float* Z1   = (const float*)d_in[0];
    const float* Z2   = (const float*)d_in[1];
    const int*   mat  = (const int*)d_in[2];
    const float* negs = (const float*)d_in[3];
    const float* Sig  = (const float*)d_in[4];
    float* ws = (float*)d_ws;
    unsigned short* S_H  = (unsigned short*)(ws + OFF_S_H);
    unsigned short* S_L  = (unsigned short*)(ws + OFF_S_L);
    unsigned short* XA_H = (unsigned short*)(ws + OFF_XA_H);
    unsigned short* XA_L = (unsigned short*)(ws + OFF_XA_L);
    unsigned short* XB_H = (unsigned short*)(ws + OFF_XB_H);
    unsigned short* XB_L = (unsigned short*)(ws + OFF_XB_L);
    unsigned short* T_H  = (unsigned short*)(ws + OFF_T_H);
    unsigned short* T_L  = (unsigned short*)(ws + OFF_T_L);
    unsigned short* PA_H = (unsigned short*)(ws + OFF_PA_H);
    unsigned short* PA_L = (unsigned short*)(ws + OFF_PA_L);
    unsigned short* NH   = (unsigned short*)(ws + OFF_NH);
    unsigned short* NL   = (unsigned short*)(ws + OFF_NL);
    unsigned* mina = (unsigned*)(ws + OFF_MINA);
    unsigned* minv = (unsigned*)(ws + OFF_MINV);
    float* out = (float*)d_out;

    kprep<<<BB, 256, 0, stream>>>(Sig, ws);

    unsigned short* pah = XA_H; unsigned short* pal = XA_L;
    unsigned short* pbh = XB_H; unsigned short* pbl = XB_L;
    for (int it = 0; it < ITERS; ++it) {
        gemm_mfma<<<dim3(32, BB), 256, 0, stream>>>(S_H, S_L, pah, pal, T_H, T_L, 1);   // T = 2I - S@X
        gemm_mfma<<<dim3(32, BB), 256, 0, stream>>>(pah, pal, T_H, T_L, pbh, pbl, 0);   // X' = X@T
        unsigned short* th = pah; pah = pbh; pbh = th;
        unsigned short* tl = pal; pal = pbl; pbl = tl;
    }
    // ITERS=5 (odd) => final split inverse in XB_H/XB_L (== pah/pal); XA/T/S now dead

    knegsplit<<<NNEG * DD / 8 / 256, 256, 0, stream>>>(negs, NH, NL, mina, minv);
    k2<<<BB * KK, 256, 0, stream>>>(Z1, Z2, mat, pah, pal, ws);
    k3<<<BB * NNEG / 128, 256, 0, stream>>>(pah, pal, PA_H, PA_L, NH, NL,
                                            ws + OFF_PAP, ws + OFF_DPOS2, mina, minv);
    k5<<<1, 256, 0, stream>>>(ws + OFF_DPOS2, mina, minv, out);
}